// Round 3
// baseline (6983.246 us; speedup 1.0000x reference)
//
#include <hip/hip_runtime.h>
#include <math.h>

constexpr int FEAT = 128;   // DIN == DH == 128

// CAS-loop float atomic add: correct on any memory type (coarse/fine), device scope.
__device__ inline void atomAddF(float* p, float v) {
    unsigned int* u = (unsigned int*)p;
    unsigned int old = *u;
    while (true) {
        unsigned int desired = __float_as_uint(__uint_as_float(old) + v);
        unsigned int prev = atomicCAS(u, old, desired);
        if (prev == old) break;
        old = prev;
    }
}

// ---------------- degree (int counts, then reciprocal in place) ----------------
__global__ void deg_kernel(const int* __restrict__ dst, int* __restrict__ degi, int E) {
    int e = blockIdx.x * 256 + threadIdx.x;
    if (e < E) atomicAdd(&degi[dst[e]], 1);
}

__global__ void inv_kernel(float* __restrict__ deg, int n) {
    int i = blockIdx.x * 256 + threadIdx.x;
    if (i < n) {
        int c = ((const int*)deg)[i];
        deg[i] = 1.0f / fmaxf((float)c, 1.0f);
    }
}

// ---------------- edge scatter (segment_sum of feat[src] by dst) ----------------
// 32 threads per edge, float4 per thread => 128 floats/edge.
__global__ void scatter_kernel(const float* feat, const int* __restrict__ src,
                               const int* __restrict__ dst, float* agg, int E) {
    int tid = blockIdx.x * 256 + threadIdx.x;
    int e = tid >> 5;
    if (e >= E) return;
    int f = (tid & 31) << 2;
    int s = src[e];
    int d = dst[e];
    float4 v = *(const float4*)(feat + (size_t)s * FEAT + f);
    float* p = agg + (size_t)d * FEAT + f;
    atomAddF(p + 0, v.x);
    atomAddF(p + 1, v.y);
    atomAddF(p + 2, v.z);
    atomAddF(p + 3, v.w);
}

// ---------------- fused dense: out = act(mean @ Wl + x @ Wr + b) ----------------
// 32 rows/block, 256 threads. Thread (tx=tid&15, ty=tid>>4) computes 2 rows x CPT cols.
// LDS: 2 x 32 x 132 x 4B = 33,792 B (< 64 KiB).
// out may alias agg (rows staged to LDS before any store; rows are block-exclusive).
template <int DOUT, bool ELU>
__global__ __launch_bounds__(256) void dense_kernel(
    const float* agg, const float* xin,
    const float* __restrict__ invd,
    const float* __restrict__ Wl, const float* __restrict__ Wr,
    const float* __restrict__ bias, float* out, int n)
{
    constexpr int ROWS = 32;
    constexpr int LDSW = FEAT + 4;      // 132
    constexpr int CPT  = DOUT / 16;     // 8 for DOUT=128, 4 for DOUT=64
    __shared__ float Am[ROWS][LDSW];
    __shared__ float Ax[ROWS][LDSW];

    const int tid  = threadIdx.x;
    const int row0 = blockIdx.x * ROWS;

    // ---- stage A tiles (mean = agg * inv_deg, and x) ----
    #pragma unroll
    for (int it = 0; it < 4; ++it) {
        int flat = (tid + it * 256) * 4;      // 0..4092, step 4
        int r = flat >> 7;                    // /128 -> 0..31
        int c = flat & 127;
        int grow = row0 + r;
        float4 va = make_float4(0.f, 0.f, 0.f, 0.f);
        float4 vx = va;
        float sc = 0.f;
        if (grow < n) {
            va = *(const float4*)(agg + (size_t)grow * FEAT + c);
            vx = *(const float4*)(xin + (size_t)grow * FEAT + c);
            sc = invd[grow];
        }
        va.x *= sc; va.y *= sc; va.z *= sc; va.w *= sc;
        *(float4*)&Am[r][c] = va;
        *(float4*)&Ax[r][c] = vx;
    }
    __syncthreads();

    const int tx = tid & 15;
    const int ty = tid >> 4;
    const int c0 = tx * CPT;

    float acc[2][CPT];
    #pragma unroll
    for (int i = 0; i < 2; ++i)
        #pragma unroll
        for (int j = 0; j < CPT; ++j) acc[i][j] = 0.f;

    for (int k = 0; k < FEAT; ++k) {
        float wl[CPT], wr[CPT];
        #pragma unroll
        for (int j = 0; j < CPT; j += 4) {
            *(float4*)&wl[j] = *(const float4*)(Wl + (size_t)k * DOUT + c0 + j);
            *(float4*)&wr[j] = *(const float4*)(Wr + (size_t)k * DOUT + c0 + j);
        }
        float am[2], ax[2];
        #pragma unroll
        for (int i = 0; i < 2; ++i) {
            am[i] = Am[ty * 2 + i][k];
            ax[i] = Ax[ty * 2 + i][k];
        }
        #pragma unroll
        for (int i = 0; i < 2; ++i)
            #pragma unroll
            for (int j = 0; j < CPT; ++j)
                acc[i][j] += am[i] * wl[j] + ax[i] * wr[j];
    }

    // ---- epilogue: bias + activation, float4 stores ----
    #pragma unroll
    for (int i = 0; i < 2; ++i) {
        int grow = row0 + ty * 2 + i;
        if (grow >= n) continue;
        #pragma unroll
        for (int j = 0; j < CPT; j += 4) {
            float4 v;
            float* vp = (float*)&v;
            #pragma unroll
            for (int q = 0; q < 4; ++q) {
                float t = acc[i][j + q] + bias[c0 + j + q];
                if (ELU) t = t > 0.f ? t : expm1f(t);
                vp[q] = t;
            }
            *(float4*)(out + (size_t)grow * DOUT + c0 + j) = v;
        }
    }
}

// ---------------- log_softmax over 64 cols, in-place ----------------
__global__ void logsoftmax_kernel(float* __restrict__ out, int n) {
    int row  = blockIdx.x * 4 + (threadIdx.x >> 6);
    int lane = threadIdx.x & 63;
    if (row >= n) return;
    float v = out[(size_t)row * 64 + lane];
    float m = v;
    #pragma unroll
    for (int s = 32; s > 0; s >>= 1) m = fmaxf(m, __shfl_xor(m, s, 64));
    float e = expf(v - m);
    float sum = e;
    #pragma unroll
    for (int s = 32; s > 0; s >>= 1) sum += __shfl_xor(sum, s, 64);
    out[(size_t)row * 64 + lane] = v - m - logf(sum);
}

extern "C" void kernel_launch(void* const* d_in, const int* in_sizes, int n_in,
                              void* d_out, int out_size, void* d_ws, size_t ws_size,
                              hipStream_t stream) {
    const float* x   = (const float*)d_in[0];
    const float* W1l = (const float*)d_in[1];
    const float* W1r = (const float*)d_in[2];
    const float* b1  = (const float*)d_in[3];
    const float* W2l = (const float*)d_in[4];
    const float* W2r = (const float*)d_in[5];
    const float* b2  = (const float*)d_in[6];
    const float* W3l = (const float*)d_in[7];
    const float* W3r = (const float*)d_in[8];
    const float* b3  = (const float*)d_in[9];
    const int*   src = (const int*)d_in[10];
    const int*   dst = (const int*)d_in[11];

    const int N = in_sizes[0] / FEAT;
    const int E = in_sizes[10];

    float* ws   = (float*)d_ws;
    float* invd = ws;
    float* buf1 = ws + (((size_t)N + 63) & ~(size_t)63);
    float* buf2 = buf1 + (size_t)N * FEAT;
    float* outp = (float*)d_out;

    const int sblocks = (E * 32 + 255) / 256;
    const int dblocks = (N + 31) / 32;

    // degrees (once): int counts -> reciprocal float in place
    hipMemsetAsync(invd, 0, (size_t)N * 4, stream);
    deg_kernel<<<(E + 255) / 256, 256, 0, stream>>>(dst, (int*)invd, E);
    inv_kernel<<<(N + 255) / 256, 256, 0, stream>>>(invd, N);

    // layer 1: buf1 = agg(x) -> h1 (in place)
    hipMemsetAsync(buf1, 0, (size_t)N * FEAT * 4, stream);
    scatter_kernel<<<sblocks, 256, 0, stream>>>(x, src, dst, buf1, E);
    dense_kernel<128, true><<<dblocks, 256, 0, stream>>>(buf1, x, invd, W1l, W1r, b1, buf1, N);

    // layer 2: buf2 = agg(h1) -> h2 (in place)
    hipMemsetAsync(buf2, 0, (size_t)N * FEAT * 4, stream);
    scatter_kernel<<<sblocks, 256, 0, stream>>>(buf1, src, dst, buf2, E);
    dense_kernel<128, true><<<dblocks, 256, 0, stream>>>(buf2, buf1, invd, W2l, W2r, b2, buf2, N);

    // layer 3: buf1 = agg(h2) -> h3 = elu(...) -> d_out, then log_softmax in place
    hipMemsetAsync(buf1, 0, (size_t)N * FEAT * 4, stream);
    scatter_kernel<<<sblocks, 256, 0, stream>>>(buf2, src, dst, buf1, E);
    dense_kernel<64, true><<<dblocks, 256, 0, stream>>>(buf1, buf2, invd, W3l, W3r, b3, outp, N);
    logsoftmax_kernel<<<(N + 3) / 4, 256, 0, stream>>>(outp, N);
}

// Round 4
// 720.052 us; speedup vs baseline: 9.6982x; 9.6982x over previous
//
#include <hip/hip_runtime.h>
#include <math.h>

constexpr int FEAT = 128;   // DIN == DH == 128

// ---------------- degree histogram (int) ----------------
__global__ void deg_kernel(const int* __restrict__ dst, int* __restrict__ degi, int E) {
    int e = blockIdx.x * 256 + threadIdx.x;
    if (e < E) atomicAdd(&degi[dst[e]], 1);
}

// ---------------- single-block exclusive scan over degrees ----------------
// Produces offs[0..n] (exclusive prefix, offs[n]=E), cur[i]=offs[i] (fill cursors),
// invd[i] = 1/max(deg,1).
__global__ __launch_bounds__(1024) void scan_kernel(const int* __restrict__ deg,
                                                    int* __restrict__ offs,
                                                    int* __restrict__ cur,
                                                    float* __restrict__ invd, int n) {
    __shared__ int part[1024];
    const int t = threadIdx.x;
    const int chunk = (n + 1023) / 1024;
    const int beg = t * chunk;
    const int end = min(beg + chunk, n);
    int sum = 0;
    for (int i = beg; i < end; ++i) sum += deg[i];
    part[t] = sum;
    __syncthreads();
    // Hillis-Steele inclusive scan (read-then-write with barriers)
    for (int s = 1; s < 1024; s <<= 1) {
        int v = (t >= s) ? part[t - s] : 0;
        __syncthreads();
        part[t] += v;
        __syncthreads();
    }
    int prefix = part[t] - sum;   // exclusive
    for (int i = beg; i < end; ++i) {
        int d = deg[i];
        offs[i] = prefix;
        cur[i]  = prefix;
        invd[i] = 1.0f / fmaxf((float)d, 1.0f);
        prefix += d;
    }
    if (t == 1023) offs[n] = part[1023];
}

// ---------------- CSR fill: eidx[] = src ids grouped by dst ----------------
__global__ void fill_kernel(const int* __restrict__ src, const int* __restrict__ dst,
                            int* __restrict__ cur, int* __restrict__ eidx, int E) {
    int e = blockIdx.x * 256 + threadIdx.x;
    if (e < E) {
        int pos = atomicAdd(&cur[dst[e]], 1);
        eidx[pos] = src[e];
    }
}

// ---------------- gather mean: one 64-lane wave per node, float2 per lane ----------------
__global__ __launch_bounds__(256) void gather_kernel(const float* __restrict__ feat,
                                                     const int* __restrict__ offs,
                                                     const int* __restrict__ eidx,
                                                     const float* __restrict__ invd,
                                                     float* __restrict__ agg, int n) {
    int node = blockIdx.x * 4 + (threadIdx.x >> 6);
    if (node >= n) return;
    int c = (threadIdx.x & 63) * 2;
    int beg = offs[node], end = offs[node + 1];
    float a0 = 0.f, a1 = 0.f;
    int j = beg;
    for (; j + 2 <= end; j += 2) {
        int s0 = eidx[j], s1 = eidx[j + 1];
        float2 v0 = *(const float2*)(feat + (size_t)s0 * FEAT + c);
        float2 v1 = *(const float2*)(feat + (size_t)s1 * FEAT + c);
        a0 += v0.x + v1.x;
        a1 += v0.y + v1.y;
    }
    if (j < end) {
        float2 v = *(const float2*)(feat + (size_t)eidx[j] * FEAT + c);
        a0 += v.x; a1 += v.y;
    }
    float sc = invd[node];
    float2 r;
    r.x = a0 * sc;
    r.y = a1 * sc;
    *(float2*)(agg + (size_t)node * FEAT + c) = r;
}

// ---------------- fused dense: out = act(mean @ Wl + x @ Wr + b) ----------------
// 32 rows/block, 256 threads. Thread (tx=tid&15, ty=tid>>4) computes 2 rows x CPT cols.
// LDS: 2 x 32 x 132 x 4B = 33,792 B. `agg` already holds the MEAN (scaled by gather).
// out may alias agg (rows staged to LDS before any store; rows are block-exclusive).
template <int DOUT, bool ELU>
__global__ __launch_bounds__(256) void dense_kernel(
    const float* agg, const float* xin,
    const float* __restrict__ Wl, const float* __restrict__ Wr,
    const float* __restrict__ bias, float* out, int n)
{
    constexpr int ROWS = 32;
    constexpr int LDSW = FEAT + 4;      // 132
    constexpr int CPT  = DOUT / 16;     // 8 for DOUT=128, 4 for DOUT=64
    __shared__ float Am[ROWS][LDSW];
    __shared__ float Ax[ROWS][LDSW];

    const int tid  = threadIdx.x;
    const int row0 = blockIdx.x * ROWS;

    #pragma unroll
    for (int it = 0; it < 4; ++it) {
        int flat = (tid + it * 256) * 4;      // 0..4092, step 4
        int r = flat >> 7;
        int c = flat & 127;
        int grow = row0 + r;
        float4 va = make_float4(0.f, 0.f, 0.f, 0.f);
        float4 vx = va;
        if (grow < n) {
            va = *(const float4*)(agg + (size_t)grow * FEAT + c);
            vx = *(const float4*)(xin + (size_t)grow * FEAT + c);
        }
        *(float4*)&Am[r][c] = va;
        *(float4*)&Ax[r][c] = vx;
    }
    __syncthreads();

    const int tx = tid & 15;
    const int ty = tid >> 4;
    const int c0 = tx * CPT;

    float acc[2][CPT];
    #pragma unroll
    for (int i = 0; i < 2; ++i)
        #pragma unroll
        for (int j = 0; j < CPT; ++j) acc[i][j] = 0.f;

    for (int k = 0; k < FEAT; ++k) {
        float wl[CPT], wr[CPT];
        #pragma unroll
        for (int j = 0; j < CPT; j += 4) {
            *(float4*)&wl[j] = *(const float4*)(Wl + (size_t)k * DOUT + c0 + j);
            *(float4*)&wr[j] = *(const float4*)(Wr + (size_t)k * DOUT + c0 + j);
        }
        float am[2], ax[2];
        #pragma unroll
        for (int i = 0; i < 2; ++i) {
            am[i] = Am[ty * 2 + i][k];
            ax[i] = Ax[ty * 2 + i][k];
        }
        #pragma unroll
        for (int i = 0; i < 2; ++i)
            #pragma unroll
            for (int j = 0; j < CPT; ++j)
                acc[i][j] += am[i] * wl[j] + ax[i] * wr[j];
    }

    #pragma unroll
    for (int i = 0; i < 2; ++i) {
        int grow = row0 + ty * 2 + i;
        if (grow >= n) continue;
        #pragma unroll
        for (int j = 0; j < CPT; j += 4) {
            float4 v;
            float* vp = (float*)&v;
            #pragma unroll
            for (int q = 0; q < 4; ++q) {
                float t = acc[i][j + q] + bias[c0 + j + q];
                if (ELU) t = t > 0.f ? t : expm1f(t);
                vp[q] = t;
            }
            *(float4*)(out + (size_t)grow * DOUT + c0 + j) = v;
        }
    }
}

// ---------------- log_softmax over 64 cols, in-place ----------------
__global__ void logsoftmax_kernel(float* __restrict__ out, int n) {
    int row  = blockIdx.x * 4 + (threadIdx.x >> 6);
    int lane = threadIdx.x & 63;
    if (row >= n) return;
    float v = out[(size_t)row * 64 + lane];
    float m = v;
    #pragma unroll
    for (int s = 32; s > 0; s >>= 1) m = fmaxf(m, __shfl_xor(m, s, 64));
    float e = expf(v - m);
    float sum = e;
    #pragma unroll
    for (int s = 32; s > 0; s >>= 1) sum += __shfl_xor(sum, s, 64);
    out[(size_t)row * 64 + lane] = v - m - logf(sum);
}

extern "C" void kernel_launch(void* const* d_in, const int* in_sizes, int n_in,
                              void* d_out, int out_size, void* d_ws, size_t ws_size,
                              hipStream_t stream) {
    const float* x   = (const float*)d_in[0];
    const float* W1l = (const float*)d_in[1];
    const float* W1r = (const float*)d_in[2];
    const float* b1  = (const float*)d_in[3];
    const float* W2l = (const float*)d_in[4];
    const float* W2r = (const float*)d_in[5];
    const float* b2  = (const float*)d_in[6];
    const float* W3l = (const float*)d_in[7];
    const float* W3r = (const float*)d_in[8];
    const float* b3  = (const float*)d_in[9];
    const int*   src = (const int*)d_in[10];
    const int*   dst = (const int*)d_in[11];

    const int N = in_sizes[0] / FEAT;
    const int E = in_sizes[10];

    const size_t NA = ((size_t)N + 63) & ~(size_t)63;     // aligned N
    const size_t EA = ((size_t)E + 63) & ~(size_t)63;

    float* ws   = (float*)d_ws;
    float* invd = ws;                       // N floats
    int*   deg  = (int*)(ws + NA);          // N ints
    int*   offs = deg + NA;                 // N+1 ints
    int*   cur  = offs + NA + 64;           // N ints
    int*   eidx = cur + NA;                 // E ints
    float* buf1 = (float*)(eidx + EA);      // N*128 floats
    float* buf2 = buf1 + NA * FEAT;         // N*128 floats
    float* outp = (float*)d_out;

    const int gblocks = (N + 3) / 4;
    const int dblocks = (N + 31) / 32;

    // ---- CSR build (once) ----
    hipMemsetAsync(deg, 0, (size_t)N * 4, stream);
    deg_kernel<<<(E + 255) / 256, 256, 0, stream>>>(dst, deg, E);
    scan_kernel<<<1, 1024, 0, stream>>>(deg, offs, cur, invd, N);
    fill_kernel<<<(E + 255) / 256, 256, 0, stream>>>(src, dst, cur, eidx, E);

    // layer 1
    gather_kernel<<<gblocks, 256, 0, stream>>>(x, offs, eidx, invd, buf1, N);
    dense_kernel<128, true><<<dblocks, 256, 0, stream>>>(buf1, x, W1l, W1r, b1, buf1, N);

    // layer 2
    gather_kernel<<<gblocks, 256, 0, stream>>>(buf1, offs, eidx, invd, buf2, N);
    dense_kernel<128, true><<<dblocks, 256, 0, stream>>>(buf2, buf1, W2l, W2r, b2, buf2, N);

    // layer 3
    gather_kernel<<<gblocks, 256, 0, stream>>>(buf2, offs, eidx, invd, buf1, N);
    dense_kernel<64, true><<<dblocks, 256, 0, stream>>>(buf1, buf2, W3l, W3r, b3, outp, N);
    logsoftmax_kernel<<<(N + 3) / 4, 256, 0, stream>>>(outp, N);
}

// Round 5
// 518.647 us; speedup vs baseline: 13.4643x; 1.3883x over previous
//
#include <hip/hip_runtime.h>
#include <math.h>

constexpr int FEAT = 128;   // DIN == DH == 128

typedef __attribute__((ext_vector_type(8))) short short8v;   // 8 bf16 raw
typedef __attribute__((ext_vector_type(4))) float f32x4;

// ---- fp32 -> bf16 (RNE) helpers ----
__device__ inline unsigned short f2bf(float f) {
    unsigned int u = __float_as_uint(f);
    u += 0x7fffu + ((u >> 16) & 1u);
    return (unsigned short)(u >> 16);
}
__device__ inline float bf2f(unsigned short h) {
    return __uint_as_float(((unsigned int)h) << 16);
}
__device__ inline void split4(float4 v, ushort4& h, ushort4& lo) {
    h.x = f2bf(v.x); lo.x = f2bf(v.x - bf2f(h.x));
    h.y = f2bf(v.y); lo.y = f2bf(v.y - bf2f(h.y));
    h.z = f2bf(v.z); lo.z = f2bf(v.z - bf2f(h.z));
    h.w = f2bf(v.w); lo.w = f2bf(v.w - bf2f(h.w));
}

// ---------------- degree histogram (int) ----------------
__global__ void deg_kernel(const int* __restrict__ dst, int* __restrict__ degi, int E) {
    int e = blockIdx.x * 256 + threadIdx.x;
    if (e < E) atomicAdd(&degi[dst[e]], 1);
}

// ---------------- single-block exclusive scan over degrees ----------------
__global__ __launch_bounds__(1024) void scan_kernel(const int* __restrict__ deg,
                                                    int* __restrict__ offs,
                                                    int* __restrict__ cur,
                                                    float* __restrict__ invd, int n) {
    __shared__ int part[1024];
    const int t = threadIdx.x;
    const int chunk = (n + 1023) / 1024;
    const int beg = t * chunk;
    const int end = min(beg + chunk, n);
    int sum = 0;
    for (int i = beg; i < end; ++i) sum += deg[i];
    part[t] = sum;
    __syncthreads();
    for (int s = 1; s < 1024; s <<= 1) {
        int v = (t >= s) ? part[t - s] : 0;
        __syncthreads();
        part[t] += v;
        __syncthreads();
    }
    int prefix = part[t] - sum;   // exclusive
    for (int i = beg; i < end; ++i) {
        int d = deg[i];
        offs[i] = prefix;
        cur[i]  = prefix;
        invd[i] = 1.0f / fmaxf((float)d, 1.0f);
        prefix += d;
    }
    if (t == 1023) offs[n] = part[1023];
}

// ---------------- CSR fill: eidx[] = src ids grouped by dst ----------------
__global__ void fill_kernel(const int* __restrict__ src, const int* __restrict__ dst,
                            int* __restrict__ cur, int* __restrict__ eidx, int E) {
    int e = blockIdx.x * 256 + threadIdx.x;
    if (e < E) {
        int pos = atomicAdd(&cur[dst[e]], 1);
        eidx[pos] = src[e];
    }
}

// ---------------- W transpose prep: WT[c][k] = concat(Wl;Wr)[k][c] ----------------
__global__ void prep_wt(const float* __restrict__ Wl, const float* __restrict__ Wr,
                        float* __restrict__ WT, int dout) {
    int idx = blockIdx.x * 256 + threadIdx.x;
    if (idx >= dout * 256) return;
    int c = idx >> 8;
    int k = idx & 255;
    float v = (k < 128) ? Wl[(size_t)k * dout + c] : Wr[(size_t)(k - 128) * dout + c];
    WT[(size_t)c * 256 + k] = v;
}

// ---------------- gather mean: one 64-lane wave per node, float2 per lane ----------------
__global__ __launch_bounds__(256) void gather_kernel(const float* __restrict__ feat,
                                                     const int* __restrict__ offs,
                                                     const int* __restrict__ eidx,
                                                     const float* __restrict__ invd,
                                                     float* __restrict__ agg, int n) {
    int node = blockIdx.x * 4 + (threadIdx.x >> 6);
    if (node >= n) return;
    int c = (threadIdx.x & 63) * 2;
    int beg = offs[node], end = offs[node + 1];
    float a0 = 0.f, a1 = 0.f;
    int j = beg;
    for (; j + 4 <= end; j += 4) {
        int s0 = eidx[j], s1 = eidx[j + 1], s2 = eidx[j + 2], s3 = eidx[j + 3];
        float2 v0 = *(const float2*)(feat + (size_t)s0 * FEAT + c);
        float2 v1 = *(const float2*)(feat + (size_t)s1 * FEAT + c);
        float2 v2 = *(const float2*)(feat + (size_t)s2 * FEAT + c);
        float2 v3 = *(const float2*)(feat + (size_t)s3 * FEAT + c);
        a0 += v0.x + v1.x + v2.x + v3.x;
        a1 += v0.y + v1.y + v2.y + v3.y;
    }
    for (; j < end; ++j) {
        float2 v = *(const float2*)(feat + (size_t)eidx[j] * FEAT + c);
        a0 += v.x; a1 += v.y;
    }
    float sc = invd[node];
    float2 r;
    r.x = a0 * sc;
    r.y = a1 * sc;
    *(float2*)(agg + (size_t)node * FEAT + c) = r;
}

// ---------------- MFMA dense: out = elu([mean|x] @ WT^T + b) ----------------
// K=256 (concat), bf16 hi/lo split (3 MFMAs, drop lo*lo) => ~fp32 accuracy.
// 128 rows/block, 4 waves x 32 rows; 8 K-chunks of 32 staged in LDS (stride 40
// ushorts = 80 B: 16B-aligned b128 frags, 8 bank-groups => <=2-way conflicts).
// out may alias mean (all reads of a block's rows precede its epilogue stores;
// rows are block-exclusive).
template <int DOUT>
__global__ __launch_bounds__(256) void dense_mfma(
    const float* mean, const float* xin,
    const float* __restrict__ WT, const float* __restrict__ bias,
    float* out, int n)
{
    constexpr int NCT = DOUT / 16;      // col tiles: 8 or 4
    constexpr int STR = 40;             // ushort stride per row
    __shared__ unsigned short Ah[128][STR];
    __shared__ unsigned short Al[128][STR];
    __shared__ unsigned short Bh[DOUT][STR];
    __shared__ unsigned short Bl[DOUT][STR];

    const int tid  = threadIdx.x;
    const int l    = tid & 63;
    const int w    = tid >> 6;
    const int row0 = blockIdx.x * 128;
    const int l15  = l & 15;
    const int lg   = l >> 4;

    f32x4 acc[2][NCT];
    #pragma unroll
    for (int rt = 0; rt < 2; ++rt)
        #pragma unroll
        for (int ct = 0; ct < NCT; ++ct)
            acc[rt][ct] = (f32x4){0.f, 0.f, 0.f, 0.f};

    for (int ch = 0; ch < 8; ++ch) {
        __syncthreads();
        // ---- stage A chunk (rows of mean for ch<4, of x for ch>=4) ----
        const float* As = (ch < 4) ? mean : xin;
        const int kb = (ch & 3) * 32;
        #pragma unroll
        for (int i = 0; i < 4; ++i) {
            int e  = (tid + i * 256) * 4;
            int r  = e >> 5;
            int kl = e & 31;
            int g  = row0 + r;
            float4 v = (g < n) ? *(const float4*)(As + (size_t)g * FEAT + kb + kl)
                               : make_float4(0.f, 0.f, 0.f, 0.f);
            ushort4 h, lo;
            split4(v, h, lo);
            *(ushort4*)&Ah[r][kl] = h;
            *(ushort4*)&Al[r][kl] = lo;
        }
        // ---- stage B chunk from WT[c][k] (k-contiguous, coalesced) ----
        #pragma unroll
        for (int i = 0; i < DOUT / 32; ++i) {
            int e  = (tid + i * 256) * 4;
            int c  = e >> 5;
            int kl = e & 31;
            float4 v = *(const float4*)(WT + (size_t)c * 256 + ch * 32 + kl);
            ushort4 h, lo;
            split4(v, h, lo);
            *(ushort4*)&Bh[c][kl] = h;
            *(ushort4*)&Bl[c][kl] = lo;
        }
        __syncthreads();

        // ---- B fragments (shared across both row tiles) ----
        short8v bh[NCT], bl[NCT];
        #pragma unroll
        for (int ct = 0; ct < NCT; ++ct) {
            int c = ct * 16 + l15;
            bh[ct] = *(const short8v*)&Bh[c][lg * 8];
            bl[ct] = *(const short8v*)&Bl[c][lg * 8];
        }
        #pragma unroll
        for (int rt = 0; rt < 2; ++rt) {
            int r = w * 32 + rt * 16 + l15;
            short8v ah = *(const short8v*)&Ah[r][lg * 8];
            short8v al = *(const short8v*)&Al[r][lg * 8];
            #pragma unroll
            for (int ct = 0; ct < NCT; ++ct) {
                acc[rt][ct] = __builtin_amdgcn_mfma_f32_16x16x32_bf16(ah, bh[ct], acc[rt][ct], 0, 0, 0);
                acc[rt][ct] = __builtin_amdgcn_mfma_f32_16x16x32_bf16(ah, bl[ct], acc[rt][ct], 0, 0, 0);
                acc[rt][ct] = __builtin_amdgcn_mfma_f32_16x16x32_bf16(al, bh[ct], acc[rt][ct], 0, 0, 0);
            }
        }
    }

    // ---- epilogue: bias + ELU, scalar stores (C/D: col=lane&15, row=(lane>>4)*4+q) ----
    #pragma unroll
    for (int rt = 0; rt < 2; ++rt) {
        #pragma unroll
        for (int ct = 0; ct < NCT; ++ct) {
            int col = ct * 16 + l15;
            float b = bias[col];
            #pragma unroll
            for (int q = 0; q < 4; ++q) {
                int grow = row0 + w * 32 + rt * 16 + lg * 4 + q;
                if (grow < n) {
                    float t = acc[rt][ct][q] + b;
                    t = (t > 0.f) ? t : expm1f(t);
                    out[(size_t)grow * DOUT + col] = t;
                }
            }
        }
    }
}

// ---------------- log_softmax over 64 cols, in-place ----------------
__global__ void logsoftmax_kernel(float* __restrict__ out, int n) {
    int row  = blockIdx.x * 4 + (threadIdx.x >> 6);
    int lane = threadIdx.x & 63;
    if (row >= n) return;
    float v = out[(size_t)row * 64 + lane];
    float m = v;
    #pragma unroll
    for (int s = 32; s > 0; s >>= 1) m = fmaxf(m, __shfl_xor(m, s, 64));
    float e = expf(v - m);
    float sum = e;
    #pragma unroll
    for (int s = 32; s > 0; s >>= 1) sum += __shfl_xor(sum, s, 64);
    out[(size_t)row * 64 + lane] = v - m - logf(sum);
}

extern "C" void kernel_launch(void* const* d_in, const int* in_sizes, int n_in,
                              void* d_out, int out_size, void* d_ws, size_t ws_size,
                              hipStream_t stream) {
    const float* x   = (const float*)d_in[0];
    const float* W1l = (const float*)d_in[1];
    const float* W1r = (const float*)d_in[2];
    const float* b1  = (const float*)d_in[3];
    const float* W2l = (const float*)d_in[4];
    const float* W2r = (const float*)d_in[5];
    const float* b2  = (const float*)d_in[6];
    const float* W3l = (const float*)d_in[7];
    const float* W3r = (const float*)d_in[8];
    const float* b3  = (const float*)d_in[9];
    const int*   src = (const int*)d_in[10];
    const int*   dst = (const int*)d_in[11];

    const int N = in_sizes[0] / FEAT;
    const int E = in_sizes[10];

    const size_t NA = ((size_t)N + 63) & ~(size_t)63;
    const size_t EA = ((size_t)E + 63) & ~(size_t)63;

    float* ws   = (float*)d_ws;
    float* invd = ws;                        // NA floats
    int*   deg  = (int*)(ws + NA);           // NA ints
    int*   offs = deg + NA;                  // NA+64 ints
    int*   cur  = offs + NA + 64;            // NA ints
    int*   eidx = cur + NA;                  // EA ints
    float* WT1  = (float*)(eidx + EA);       // 128*256
    float* WT2  = WT1 + 128 * 256;           // 128*256
    float* WT3  = WT2 + 128 * 256;           // 64*256
    float* bufM = WT3 + 64 * 256;            // NA*128
    float* bufB = bufM + NA * FEAT;          // NA*128
    float* outp = (float*)d_out;

    const int gblocks = (N + 3) / 4;
    const int dblocks = (N + 127) / 128;

    // ---- CSR build + W transposes (once) ----
    hipMemsetAsync(deg, 0, (size_t)N * 4, stream);
    deg_kernel<<<(E + 255) / 256, 256, 0, stream>>>(dst, deg, E);
    scan_kernel<<<1, 1024, 0, stream>>>(deg, offs, cur, invd, N);
    fill_kernel<<<(E + 255) / 256, 256, 0, stream>>>(src, dst, cur, eidx, E);
    prep_wt<<<(128 * 256 + 255) / 256, 256, 0, stream>>>(W1l, W1r, WT1, 128);
    prep_wt<<<(128 * 256 + 255) / 256, 256, 0, stream>>>(W2l, W2r, WT2, 128);
    prep_wt<<<(64 * 256 + 255) / 256, 256, 0, stream>>>(W3l, W3r, WT3, 64);

    // layer 1: gather(x)->M ; h1 = dense(M, x) -> M (alias OK)
    gather_kernel<<<gblocks, 256, 0, stream>>>(x, offs, eidx, invd, bufM, N);
    dense_mfma<128><<<dblocks, 256, 0, stream>>>(bufM, x, WT1, b1, bufM, N);

    // layer 2: gather(h1=M)->B ; h2 = dense(B, M) -> B
    gather_kernel<<<gblocks, 256, 0, stream>>>(bufM, offs, eidx, invd, bufB, N);
    dense_mfma<128><<<dblocks, 256, 0, stream>>>(bufB, bufM, WT2, b2, bufB, N);

    // layer 3: gather(h2=B)->M ; out = dense(M, B) -> d_out
    gather_kernel<<<gblocks, 256, 0, stream>>>(bufB, offs, eidx, invd, bufM, N);
    dense_mfma<64><<<dblocks, 256, 0, stream>>>(bufM, bufB, WT3, b3, outp, N);
    logsoftmax_kernel<<<(N + 3) / 4, 256, 0, stream>>>(outp, N);
}

// Round 6
// 351.229 us; speedup vs baseline: 19.8823x; 1.4767x over previous
//
#include <hip/hip_runtime.h>
#include <math.h>

constexpr int FEAT = 128;   // DIN == DH == 128

typedef __attribute__((ext_vector_type(8))) short short8v;   // 8 bf16 raw
typedef __attribute__((ext_vector_type(4))) float f32x4;

// ---- fp32 -> bf16 (RNE) helpers ----
__device__ inline unsigned short f2bf(float f) {
    unsigned int u = __float_as_uint(f);
    u += 0x7fffu + ((u >> 16) & 1u);
    return (unsigned short)(u >> 16);
}
__device__ inline float bf2f(unsigned short h) {
    return __uint_as_float(((unsigned int)h) << 16);
}
__device__ inline void split4(float4 v, ushort4& h, ushort4& lo) {
    h.x = f2bf(v.x); lo.x = f2bf(v.x - bf2f(h.x));
    h.y = f2bf(v.y); lo.y = f2bf(v.y - bf2f(h.y));
    h.z = f2bf(v.z); lo.z = f2bf(v.z - bf2f(h.z));
    h.w = f2bf(v.w); lo.w = f2bf(v.w - bf2f(h.w));
}

// ---------------- degree histogram (int) ----------------
__global__ void deg_kernel(const int* __restrict__ dst, int* __restrict__ degi, int E) {
    int e = blockIdx.x * 256 + threadIdx.x;
    if (e < E) atomicAdd(&degi[dst[e]], 1);
}

// ---------------- hierarchical exclusive scan (1024 elems / block) ----------------
__global__ __launch_bounds__(256) void blockred_kernel(const int* __restrict__ deg,
                                                       int* __restrict__ bsum, int n) {
    __shared__ int red[256];
    int base = blockIdx.x * 1024 + threadIdx.x * 4;
    int s = 0;
    if (base + 3 < n) {
        int4 v = *(const int4*)(deg + base);
        s = v.x + v.y + v.z + v.w;
    } else {
        for (int i = 0; i < 4; ++i) if (base + i < n) s += deg[base + i];
    }
    red[threadIdx.x] = s;
    __syncthreads();
    for (int st = 128; st > 0; st >>= 1) {
        if (threadIdx.x < st) red[threadIdx.x] += red[threadIdx.x + st];
        __syncthreads();
    }
    if (threadIdx.x == 0) bsum[blockIdx.x] = red[0];
}

// 1 block, 256 threads; nb <= 256 (N <= 262144)
__global__ __launch_bounds__(256) void scanb_kernel(const int* __restrict__ bsum,
                                                    int* __restrict__ bpre, int nb) {
    __shared__ int part[256];
    int t = threadIdx.x;
    int v = (t < nb) ? bsum[t] : 0;
    part[t] = v;
    __syncthreads();
    for (int s = 1; s < 256; s <<= 1) {
        int u = (t >= s) ? part[t - s] : 0;
        __syncthreads();
        part[t] += u;
        __syncthreads();
    }
    if (t < nb) bpre[t] = part[t] - v;
}

__global__ __launch_bounds__(256) void scanfill_kernel(const int* __restrict__ deg,
                                                       const int* __restrict__ bpre,
                                                       int* __restrict__ offs,
                                                       int* __restrict__ cur,
                                                       float* __restrict__ invd,
                                                       int n, int E) {
    __shared__ int part[256];
    int t = threadIdx.x;
    int base = blockIdx.x * 1024 + t * 4;
    int d[4];
    int s = 0;
    #pragma unroll
    for (int i = 0; i < 4; ++i) {
        d[i] = (base + i < n) ? deg[base + i] : 0;
        s += d[i];
    }
    part[t] = s;
    __syncthreads();
    for (int st = 1; st < 256; st <<= 1) {
        int u = (t >= st) ? part[t - st] : 0;
        __syncthreads();
        part[t] += u;
        __syncthreads();
    }
    int pre = bpre[blockIdx.x] + part[t] - s;
    #pragma unroll
    for (int i = 0; i < 4; ++i) {
        int idx = base + i;
        if (idx < n) {
            offs[idx] = pre;
            cur[idx]  = pre;
            invd[idx] = 1.0f / fmaxf((float)d[i], 1.0f);
            pre += d[i];
        }
    }
    if (blockIdx.x == 0 && t == 0) offs[n] = E;
}

// ---------------- CSR fill: eidx[] = src ids grouped by dst ----------------
__global__ void fill_kernel(const int* __restrict__ src, const int* __restrict__ dst,
                            int* __restrict__ cur, int* __restrict__ eidx, int E) {
    int e = blockIdx.x * 256 + threadIdx.x;
    if (e < E) {
        int pos = atomicAdd(&cur[dst[e]], 1);
        eidx[pos] = src[e];
    }
}

// ---------------- W transpose prep: WT[c][k] = concat(Wl;Wr)[k][c] ----------------
__global__ void prep_wt(const float* __restrict__ Wl, const float* __restrict__ Wr,
                        float* __restrict__ WT, int dout) {
    int idx = blockIdx.x * 256 + threadIdx.x;
    if (idx >= dout * 256) return;
    int c = idx >> 8;
    int k = idx & 255;
    float v = (k < 128) ? Wl[(size_t)k * dout + c] : Wr[(size_t)(k - 128) * dout + c];
    WT[(size_t)c * 256 + k] = v;
}

// ---------------- fp32 -> bf16 convert (x -> xbf) ----------------
__global__ void f2bf_kernel(const float* __restrict__ in, unsigned short* __restrict__ out,
                            int total4) {
    int i = blockIdx.x * 256 + threadIdx.x;
    if (i >= total4) return;
    float4 v = *(const float4*)(in + (size_t)i * 4);
    ushort4 h;
    h.x = f2bf(v.x); h.y = f2bf(v.y); h.z = f2bf(v.z); h.w = f2bf(v.w);
    *(ushort4*)(out + (size_t)i * 4) = h;
}

// ---------------- gather mean from bf16 feats: one wave per node ----------------
__global__ __launch_bounds__(256) void gather_bf_kernel(const unsigned short* __restrict__ featbf,
                                                        const int* __restrict__ offs,
                                                        const int* __restrict__ eidx,
                                                        const float* __restrict__ invd,
                                                        float* __restrict__ agg, int n) {
    int node = blockIdx.x * 4 + (threadIdx.x >> 6);
    if (node >= n) return;
    int c = (threadIdx.x & 63) * 2;
    int beg = offs[node], end = offs[node + 1];
    float a0 = 0.f, a1 = 0.f;
    int j = beg;
    for (; j + 8 <= end; j += 8) {
        unsigned int v[8];
        #pragma unroll
        for (int q = 0; q < 8; ++q)
            v[q] = *(const unsigned int*)(featbf + (size_t)eidx[j + q] * FEAT + c);
        #pragma unroll
        for (int q = 0; q < 8; ++q) {
            a0 += __uint_as_float(v[q] << 16);
            a1 += __uint_as_float(v[q] & 0xffff0000u);
        }
    }
    for (; j < end; ++j) {
        unsigned int v = *(const unsigned int*)(featbf + (size_t)eidx[j] * FEAT + c);
        a0 += __uint_as_float(v << 16);
        a1 += __uint_as_float(v & 0xffff0000u);
    }
    float sc = invd[node];
    float2 r;
    r.x = a0 * sc;
    r.y = a1 * sc;
    *(float2*)(agg + (size_t)node * FEAT + c) = r;
}

// ---------------- MFMA dense: out = elu([mean|x] @ WT^T + b) ----------------
// K=256 (concat), bf16 hi/lo split (3 MFMAs, drop lo*lo) => ~fp32 accuracy.
// 128 rows/block, 4 waves x 32 rows; 8 K-chunks of 32 staged in LDS (stride 40
// ushorts). out may alias mean (reads precede epilogue stores; rows block-exclusive).
// If WBF: also write bf16 copy of the activation (for the next layer's gather).
template <int DOUT, bool WBF>
__global__ __launch_bounds__(256) void dense_mfma(
    const float* mean, const float* xin,
    const float* __restrict__ WT, const float* __restrict__ bias,
    float* out, unsigned short* outbf, int n)
{
    constexpr int NCT = DOUT / 16;      // col tiles: 8 or 4
    constexpr int STR = 40;             // ushort stride per row
    __shared__ unsigned short Ah[128][STR];
    __shared__ unsigned short Al[128][STR];
    __shared__ unsigned short Bh[DOUT][STR];
    __shared__ unsigned short Bl[DOUT][STR];

    const int tid  = threadIdx.x;
    const int l    = tid & 63;
    const int w    = tid >> 6;
    const int row0 = blockIdx.x * 128;
    const int l15  = l & 15;
    const int lg   = l >> 4;

    f32x4 acc[2][NCT];
    #pragma unroll
    for (int rt = 0; rt < 2; ++rt)
        #pragma unroll
        for (int ct = 0; ct < NCT; ++ct)
            acc[rt][ct] = (f32x4){0.f, 0.f, 0.f, 0.f};

    for (int ch = 0; ch < 8; ++ch) {
        __syncthreads();
        const float* As = (ch < 4) ? mean : xin;
        const int kb = (ch & 3) * 32;
        #pragma unroll
        for (int i = 0; i < 4; ++i) {
            int e  = (tid + i * 256) * 4;
            int r  = e >> 5;
            int kl = e & 31;
            int g  = row0 + r;
            float4 v = (g < n) ? *(const float4*)(As + (size_t)g * FEAT + kb + kl)
                               : make_float4(0.f, 0.f, 0.f, 0.f);
            ushort4 h, lo;
            split4(v, h, lo);
            *(ushort4*)&Ah[r][kl] = h;
            *(ushort4*)&Al[r][kl] = lo;
        }
        #pragma unroll
        for (int i = 0; i < DOUT / 32; ++i) {
            int e  = (tid + i * 256) * 4;
            int c  = e >> 5;
            int kl = e & 31;
            float4 v = *(const float4*)(WT + (size_t)c * 256 + ch * 32 + kl);
            ushort4 h, lo;
            split4(v, h, lo);
            *(ushort4*)&Bh[c][kl] = h;
            *(ushort4*)&Bl[c][kl] = lo;
        }
        __syncthreads();

        short8v bh[NCT], bl[NCT];
        #pragma unroll
        for (int ct = 0; ct < NCT; ++ct) {
            int c = ct * 16 + l15;
            bh[ct] = *(const short8v*)&Bh[c][lg * 8];
            bl[ct] = *(const short8v*)&Bl[c][lg * 8];
        }
        #pragma unroll
        for (int rt = 0; rt < 2; ++rt) {
            int r = w * 32 + rt * 16 + l15;
            short8v ah = *(const short8v*)&Ah[r][lg * 8];
            short8v al = *(const short8v*)&Al[r][lg * 8];
            #pragma unroll
            for (int ct = 0; ct < NCT; ++ct) {
                acc[rt][ct] = __builtin_amdgcn_mfma_f32_16x16x32_bf16(ah, bh[ct], acc[rt][ct], 0, 0, 0);
                acc[rt][ct] = __builtin_amdgcn_mfma_f32_16x16x32_bf16(ah, bl[ct], acc[rt][ct], 0, 0, 0);
                acc[rt][ct] = __builtin_amdgcn_mfma_f32_16x16x32_bf16(al, bh[ct], acc[rt][ct], 0, 0, 0);
            }
        }
    }

    // ---- epilogue: bias + ELU (C/D: col=lane&15, row=(lane>>4)*4+q) ----
    #pragma unroll
    for (int rt = 0; rt < 2; ++rt) {
        #pragma unroll
        for (int ct = 0; ct < NCT; ++ct) {
            int col = ct * 16 + l15;
            float b = bias[col];
            #pragma unroll
            for (int q = 0; q < 4; ++q) {
                int grow = row0 + w * 32 + rt * 16 + lg * 4 + q;
                if (grow < n) {
                    float t = acc[rt][ct][q] + b;
                    t = (t > 0.f) ? t : expm1f(t);
                    out[(size_t)grow * DOUT + col] = t;
                    if (WBF) outbf[(size_t)grow * DOUT + col] = f2bf(t);
                }
            }
        }
    }
}

// ---------------- log_softmax over 64 cols, in-place ----------------
__global__ void logsoftmax_kernel(float* __restrict__ out, int n) {
    int row  = blockIdx.x * 4 + (threadIdx.x >> 6);
    int lane = threadIdx.x & 63;
    if (row >= n) return;
    float v = out[(size_t)row * 64 + lane];
    float m = v;
    #pragma unroll
    for (int s = 32; s > 0; s >>= 1) m = fmaxf(m, __shfl_xor(m, s, 64));
    float e = expf(v - m);
    float sum = e;
    #pragma unroll
    for (int s = 32; s > 0; s >>= 1) sum += __shfl_xor(sum, s, 64);
    out[(size_t)row * 64 + lane] = v - m - logf(sum);
}

extern "C" void kernel_launch(void* const* d_in, const int* in_sizes, int n_in,
                              void* d_out, int out_size, void* d_ws, size_t ws_size,
                              hipStream_t stream) {
    const float* x   = (const float*)d_in[0];
    const float* W1l = (const float*)d_in[1];
    const float* W1r = (const float*)d_in[2];
    const float* b1  = (const float*)d_in[3];
    const float* W2l = (const float*)d_in[4];
    const float* W2r = (const float*)d_in[5];
    const float* b2  = (const float*)d_in[6];
    const float* W3l = (const float*)d_in[7];
    const float* W3r = (const float*)d_in[8];
    const float* b3  = (const float*)d_in[9];
    const int*   src = (const int*)d_in[10];
    const int*   dst = (const int*)d_in[11];

    const int N = in_sizes[0] / FEAT;
    const int E = in_sizes[10];

    const size_t NA = ((size_t)N + 63) & ~(size_t)63;
    const size_t EA = ((size_t)E + 63) & ~(size_t)63;
    const int nb = (N + 1023) / 1024;       // scan blocks (<=256)

    float* ws   = (float*)d_ws;
    float* invd = ws;                             // NA floats
    int*   deg  = (int*)(ws + NA);                // NA ints
    int*   offs = deg + NA;                       // NA+64 ints
    int*   cur  = offs + NA + 64;                 // NA ints
    int*   bsum = cur + NA;                       // 256 ints
    int*   bpre = bsum + 256;                     // 256 ints
    int*   eidx = bpre + 256;                     // EA ints
    float* WT1  = (float*)(eidx + EA);            // 128*256
    float* WT2  = WT1 + 128 * 256;                // 128*256
    float* WT3  = WT2 + 128 * 256;                // 64*256
    float* bufA = WT3 + 64 * 256;                 // NA*128 fp32
    float* bufB = bufA + NA * FEAT;               // NA*128 fp32
    unsigned short* hbf = (unsigned short*)(bufB + NA * FEAT);   // NA*128 bf16
    float* outp = (float*)d_out;

    const int gblocks = (N + 3) / 4;
    const int dblocks = (N + 127) / 128;

    // ---- CSR build + weight prep (once per launch) ----
    hipMemsetAsync(deg, 0, (size_t)N * 4, stream);
    deg_kernel<<<(E + 255) / 256, 256, 0, stream>>>(dst, deg, E);
    blockred_kernel<<<nb, 256, 0, stream>>>(deg, bsum, N);
    scanb_kernel<<<1, 256, 0, stream>>>(bsum, bpre, nb);
    scanfill_kernel<<<nb, 256, 0, stream>>>(deg, bpre, offs, cur, invd, N, E);
    fill_kernel<<<(E + 255) / 256, 256, 0, stream>>>(src, dst, cur, eidx, E);
    prep_wt<<<(128 * 256 + 255) / 256, 256, 0, stream>>>(W1l, W1r, WT1, 128);
    prep_wt<<<(128 * 256 + 255) / 256, 256, 0, stream>>>(W2l, W2r, WT2, 128);
    prep_wt<<<(64 * 256 + 255) / 256, 256, 0, stream>>>(W3l, W3r, WT3, 64);
    f2bf_kernel<<<(N * FEAT / 4 + 255) / 256, 256, 0, stream>>>(x, hbf, N * FEAT / 4);

    // layer 1: gather(xbf) -> A ; h1 = dense(A, x) -> A (fp32) + hbf (bf16)
    gather_bf_kernel<<<gblocks, 256, 0, stream>>>(hbf, offs, eidx, invd, bufA, N);
    dense_mfma<128, true><<<dblocks, 256, 0, stream>>>(bufA, x, WT1, b1, bufA, hbf, N);

    // layer 2: gather(h1bf) -> B ; h2 = dense(B, h1) -> B (fp32) + hbf (bf16)
    gather_bf_kernel<<<gblocks, 256, 0, stream>>>(hbf, offs, eidx, invd, bufB, N);
    dense_mfma<128, true><<<dblocks, 256, 0, stream>>>(bufB, bufA, WT2, b2, bufB, hbf, N);

    // layer 3: gather(h2bf) -> A ; out = dense(A, h2) -> d_out ; log_softmax
    gather_bf_kernel<<<gblocks, 256, 0, stream>>>(hbf, offs, eidx, invd, bufA, N);
    dense_mfma<64, false><<<dblocks, 256, 0, stream>>>(bufA, bufB, WT3, b3, outp, nullptr, N);
    logsoftmax_kernel<<<(N + 3) / 4, 256, 0, stream>>>(outp, N);
}

// Round 7
// 351.146 us; speedup vs baseline: 19.8870x; 1.0002x over previous
//
#include <hip/hip_runtime.h>
#include <math.h>

constexpr int FEAT = 128;   // DIN == DH == 128

typedef __attribute__((ext_vector_type(8))) short short8v;   // 8 bf16 raw
typedef __attribute__((ext_vector_type(4))) float f32x4;

// ---- fp32 -> bf16 (RNE) helpers ----
__device__ inline unsigned short f2bf(float f) {
    unsigned int u = __float_as_uint(f);
    u += 0x7fffu + ((u >> 16) & 1u);
    return (unsigned short)(u >> 16);
}
__device__ inline float bf2f(unsigned short h) {
    return __uint_as_float(((unsigned int)h) << 16);
}
__device__ inline void split8(const float4 v0, const float4 v1, short8v& h, short8v& lo) {
    const float* f = (const float*)&v0;
    unsigned short hh[8], ll[8];
    #pragma unroll
    for (int i = 0; i < 4; ++i) {
        hh[i] = f2bf(f[i]); ll[i] = f2bf(f[i] - bf2f(hh[i]));
    }
    const float* g = (const float*)&v1;
    #pragma unroll
    for (int i = 0; i < 4; ++i) {
        hh[4 + i] = f2bf(g[i]); ll[4 + i] = f2bf(g[i] - bf2f(hh[4 + i]));
    }
    h  = *(short8v*)hh;
    lo = *(short8v*)ll;
}

// ---------------- degree histogram (int) ----------------
__global__ void deg_kernel(const int* __restrict__ dst, int* __restrict__ degi, int E) {
    int e = blockIdx.x * 256 + threadIdx.x;
    if (e < E) atomicAdd(&degi[dst[e]], 1);
}

// ---------------- hierarchical exclusive scan (1024 elems / block) ----------------
__global__ __launch_bounds__(256) void blockred_kernel(const int* __restrict__ deg,
                                                       int* __restrict__ bsum, int n) {
    __shared__ int red[256];
    int base = blockIdx.x * 1024 + threadIdx.x * 4;
    int s = 0;
    if (base + 3 < n) {
        int4 v = *(const int4*)(deg + base);
        s = v.x + v.y + v.z + v.w;
    } else {
        for (int i = 0; i < 4; ++i) if (base + i < n) s += deg[base + i];
    }
    red[threadIdx.x] = s;
    __syncthreads();
    for (int st = 128; st > 0; st >>= 1) {
        if (threadIdx.x < st) red[threadIdx.x] += red[threadIdx.x + st];
        __syncthreads();
    }
    if (threadIdx.x == 0) bsum[blockIdx.x] = red[0];
}

// 1 block, 256 threads; nb <= 256 (N <= 262144)
__global__ __launch_bounds__(256) void scanb_kernel(const int* __restrict__ bsum,
                                                    int* __restrict__ bpre, int nb) {
    __shared__ int part[256];
    int t = threadIdx.x;
    int v = (t < nb) ? bsum[t] : 0;
    part[t] = v;
    __syncthreads();
    for (int s = 1; s < 256; s <<= 1) {
        int u = (t >= s) ? part[t - s] : 0;
        __syncthreads();
        part[t] += u;
        __syncthreads();
    }
    if (t < nb) bpre[t] = part[t] - v;
}

__global__ __launch_bounds__(256) void scanfill_kernel(const int* __restrict__ deg,
                                                       const int* __restrict__ bpre,
                                                       int* __restrict__ offs,
                                                       int* __restrict__ cur,
                                                       float* __restrict__ invd,
                                                       int n, int E) {
    __shared__ int part[256];
    int t = threadIdx.x;
    int base = blockIdx.x * 1024 + t * 4;
    int d[4];
    int s = 0;
    #pragma unroll
    for (int i = 0; i < 4; ++i) {
        d[i] = (base + i < n) ? deg[base + i] : 0;
        s += d[i];
    }
    part[t] = s;
    __syncthreads();
    for (int st = 1; st < 256; st <<= 1) {
        int u = (t >= st) ? part[t - st] : 0;
        __syncthreads();
        part[t] += u;
        __syncthreads();
    }
    int pre = bpre[blockIdx.x] + part[t] - s;
    #pragma unroll
    for (int i = 0; i < 4; ++i) {
        int idx = base + i;
        if (idx < n) {
            offs[idx] = pre;
            cur[idx]  = pre;
            invd[idx] = 1.0f / fmaxf((float)d[i], 1.0f);
            pre += d[i];
        }
    }
    if (blockIdx.x == 0 && t == 0) offs[n] = E;
}

// ---------------- CSR fill, dst-range partitioned (pass = blockIdx.y) ----------------
// Each pass only writes eidx positions belonging to dst in [pass*8192, (pass+1)*8192):
// a ~0.5 MB region that stays L2-resident -> write lines get fully populated.
__global__ void fill_kernel(const int* __restrict__ src, const int* __restrict__ dst,
                            int* __restrict__ cur, int* __restrict__ eidx, int E) {
    int e = blockIdx.x * 256 + threadIdx.x;
    if (e >= E) return;
    int d = dst[e];
    if ((d >> 13) != (int)blockIdx.y) return;
    int pos = atomicAdd(&cur[d], 1);
    eidx[pos] = src[e];
}

// ---------------- W prep: split bf16 transpose WTh/WTl[c][k] of concat(Wl;Wr) ----------------
__global__ void prep_wt(const float* __restrict__ Wl, const float* __restrict__ Wr,
                        unsigned short* __restrict__ WTh, unsigned short* __restrict__ WTl,
                        int dout) {
    int idx = blockIdx.x * 256 + threadIdx.x;
    if (idx >= dout * 256) return;
    int c = idx >> 8;
    int k = idx & 255;
    float v = (k < 128) ? Wl[(size_t)k * dout + c] : Wr[(size_t)(k - 128) * dout + c];
    unsigned short h = f2bf(v);
    WTh[(size_t)c * 256 + k] = h;
    WTl[(size_t)c * 256 + k] = f2bf(v - bf2f(h));
}

// ---------------- fp32 -> bf16 convert (x -> xbf) ----------------
__global__ void f2bf_kernel(const float* __restrict__ in, unsigned short* __restrict__ out,
                            int total4) {
    int i = blockIdx.x * 256 + threadIdx.x;
    if (i >= total4) return;
    float4 v = *(const float4*)(in + (size_t)i * 4);
    ushort4 h;
    h.x = f2bf(v.x); h.y = f2bf(v.y); h.z = f2bf(v.z); h.w = f2bf(v.w);
    *(ushort4*)(out + (size_t)i * 4) = h;
}

// ---------------- gather mean from bf16 feats: one wave per node ----------------
__global__ __launch_bounds__(256) void gather_bf_kernel(const unsigned short* __restrict__ featbf,
                                                        const int* __restrict__ offs,
                                                        const int* __restrict__ eidx,
                                                        const float* __restrict__ invd,
                                                        float* __restrict__ agg, int n) {
    int node = blockIdx.x * 4 + (threadIdx.x >> 6);
    if (node >= n) return;
    int c = (threadIdx.x & 63) * 2;
    int beg = offs[node], end = offs[node + 1];
    float a0 = 0.f, a1 = 0.f;
    int j = beg;
    for (; j + 8 <= end; j += 8) {
        unsigned int v[8];
        #pragma unroll
        for (int q = 0; q < 8; ++q)
            v[q] = *(const unsigned int*)(featbf + (size_t)eidx[j + q] * FEAT + c);
        #pragma unroll
        for (int q = 0; q < 8; ++q) {
            a0 += __uint_as_float(v[q] << 16);
            a1 += __uint_as_float(v[q] & 0xffff0000u);
        }
    }
    for (; j < end; ++j) {
        unsigned int v = *(const unsigned int*)(featbf + (size_t)eidx[j] * FEAT + c);
        a0 += __uint_as_float(v << 16);
        a1 += __uint_as_float(v & 0xffff0000u);
    }
    float sc = invd[node];
    float2 r;
    r.x = a0 * sc;
    r.y = a1 * sc;
    *(float2*)(agg + (size_t)node * FEAT + c) = r;
}

// ---------------- MFMA dense, register-only (no LDS, no barriers) ----------------
// out = elu([mean|x] @ W + b); K=256, bf16 hi/lo split (3 MFMAs, drop lo*lo).
// 128 rows/block, 4 waves x 32 rows; each wave loads its own A fragments from
// global (rows are wave-exclusive), B from pre-split WTh/WTl (L1/L2 resident).
// If WBF: also write bf16 activation copy. If LSM: fuse log_softmax (DOUT=64).
// out may alias mean: each wave's A reads complete (register deps) before its
// epilogue stores, and rows are wave-exclusive.
template <int DOUT, bool WBF, bool LSM>
__global__ __launch_bounds__(256) void dense_mfma(
    const float* mean, const float* xin,
    const unsigned short* __restrict__ WTh, const unsigned short* __restrict__ WTl,
    const float* __restrict__ bias,
    float* out, unsigned short* outbf, int n)
{
    constexpr int NCT = DOUT / 16;      // col tiles: 8 or 4
    const int tid  = threadIdx.x;
    const int l    = tid & 63;
    const int w    = tid >> 6;
    const int l15  = l & 15;
    const int lg   = l >> 4;
    const int row0 = blockIdx.x * 128 + w * 32;

    f32x4 acc[2][NCT];
    #pragma unroll
    for (int rt = 0; rt < 2; ++rt)
        #pragma unroll
        for (int ct = 0; ct < NCT; ++ct)
            acc[rt][ct] = (f32x4){0.f, 0.f, 0.f, 0.f};

    #pragma unroll
    for (int ch = 0; ch < 8; ++ch) {
        const float* As = (ch < 4) ? mean : xin;
        const int kb = (ch & 3) * 32 + lg * 8;
        short8v ah[2], al[2];
        #pragma unroll
        for (int rt = 0; rt < 2; ++rt) {
            int g = row0 + rt * 16 + l15;
            float4 v0 = make_float4(0.f, 0.f, 0.f, 0.f), v1 = v0;
            if (g < n) {
                const float* p = As + (size_t)g * FEAT + kb;
                v0 = *(const float4*)p;
                v1 = *(const float4*)(p + 4);
            }
            split8(v0, v1, ah[rt], al[rt]);
        }
        #pragma unroll
        for (int ct = 0; ct < NCT; ++ct) {
            const size_t boff = (size_t)(ct * 16 + l15) * 256 + ch * 32 + lg * 8;
            short8v bh = *(const short8v*)(WTh + boff);
            short8v bl = *(const short8v*)(WTl + boff);
            #pragma unroll
            for (int rt = 0; rt < 2; ++rt) {
                acc[rt][ct] = __builtin_amdgcn_mfma_f32_16x16x32_bf16(ah[rt], bh, acc[rt][ct], 0, 0, 0);
                acc[rt][ct] = __builtin_amdgcn_mfma_f32_16x16x32_bf16(ah[rt], bl, acc[rt][ct], 0, 0, 0);
                acc[rt][ct] = __builtin_amdgcn_mfma_f32_16x16x32_bf16(al[rt], bh, acc[rt][ct], 0, 0, 0);
            }
        }
    }

    // ---- epilogue: bias + ELU (+ optional fused log_softmax), C/D layout:
    // col = ct*16 + l15, row(in-tile) = lg*4 + q ----
    #pragma unroll
    for (int rt = 0; rt < 2; ++rt) {
        float t[NCT][4];
        #pragma unroll
        for (int ct = 0; ct < NCT; ++ct) {
            float b = bias[ct * 16 + l15];
            #pragma unroll
            for (int q = 0; q < 4; ++q) {
                float v = acc[rt][ct][q] + b;
                t[ct][q] = (v > 0.f) ? v : expm1f(v);
            }
        }
        if (LSM) {
            #pragma unroll
            for (int q = 0; q < 4; ++q) {
                float m = t[0][q];
                #pragma unroll
                for (int ct = 1; ct < NCT; ++ct) m = fmaxf(m, t[ct][q]);
                #pragma unroll
                for (int s = 1; s < 16; s <<= 1) m = fmaxf(m, __shfl_xor(m, s, 64));
                float sum = 0.f;
                #pragma unroll
                for (int ct = 0; ct < NCT; ++ct) sum += expf(t[ct][q] - m);
                #pragma unroll
                for (int s = 1; s < 16; s <<= 1) sum += __shfl_xor(sum, s, 64);
                float ls = m + logf(sum);
                #pragma unroll
                for (int ct = 0; ct < NCT; ++ct) t[ct][q] -= ls;
            }
        }
        #pragma unroll
        for (int ct = 0; ct < NCT; ++ct) {
            int col = ct * 16 + l15;
            #pragma unroll
            for (int q = 0; q < 4; ++q) {
                int grow = row0 + rt * 16 + lg * 4 + q;
                if (grow < n) {
                    out[(size_t)grow * DOUT + col] = t[ct][q];
                    if (WBF) outbf[(size_t)grow * DOUT + col] = f2bf(t[ct][q]);
                }
            }
        }
    }
}

extern "C" void kernel_launch(void* const* d_in, const int* in_sizes, int n_in,
                              void* d_out, int out_size, void* d_ws, size_t ws_size,
                              hipStream_t stream) {
    const float* x   = (const float*)d_in[0];
    const float* W1l = (const float*)d_in[1];
    const float* W1r = (const float*)d_in[2];
    const float* b1  = (const float*)d_in[3];
    const float* W2l = (const float*)d_in[4];
    const float* W2r = (const float*)d_in[5];
    const float* b2  = (const float*)d_in[6];
    const float* W3l = (const float*)d_in[7];
    const float* W3r = (const float*)d_in[8];
    const float* b3  = (const float*)d_in[9];
    const int*   src = (const int*)d_in[10];
    const int*   dst = (const int*)d_in[11];

    const int N = in_sizes[0] / FEAT;
    const int E = in_sizes[10];

    const size_t NA = ((size_t)N + 63) & ~(size_t)63;
    const size_t EA = ((size_t)E + 63) & ~(size_t)63;
    const int nb = (N + 1023) / 1024;       // scan blocks (<=256)
    const int npass = (N + 8191) >> 13;     // fill dst-range passes

    float* ws   = (float*)d_ws;
    float* invd = ws;                             // NA floats
    int*   deg  = (int*)(ws + NA);                // NA ints
    int*   offs = deg + NA;                       // NA+64 ints
    int*   cur  = offs + NA + 64;                 // NA ints
    int*   bsum = cur + NA;                       // 256 ints
    int*   bpre = bsum + 256;                     // 256 ints
    int*   eidx = bpre + 256;                     // EA ints
    unsigned short* wtb = (unsigned short*)(eidx + EA);
    unsigned short* WTh1 = wtb;                   // 128*256
    unsigned short* WTl1 = WTh1 + 128 * 256;
    unsigned short* WTh2 = WTl1 + 128 * 256;
    unsigned short* WTl2 = WTh2 + 128 * 256;
    unsigned short* WTh3 = WTl2 + 128 * 256;      // 64*256
    unsigned short* WTl3 = WTh3 + 64 * 256;
    float* bufA = (float*)(WTl3 + 64 * 256);      // NA*128 fp32 (16B-aligned: offset multiple of 16)
    float* bufB = bufA + NA * FEAT;               // NA*128 fp32
    unsigned short* hbf = (unsigned short*)(bufB + NA * FEAT);   // NA*128 bf16
    float* outp = (float*)d_out;

    const int gblocks = (N + 3) / 4;
    const int dblocks = (N + 127) / 128;

    // ---- CSR build + weight prep (once per launch) ----
    hipMemsetAsync(deg, 0, (size_t)N * 4, stream);
    deg_kernel<<<(E + 255) / 256, 256, 0, stream>>>(dst, deg, E);
    blockred_kernel<<<nb, 256, 0, stream>>>(deg, bsum, N);
    scanb_kernel<<<1, 256, 0, stream>>>(bsum, bpre, nb);
    scanfill_kernel<<<nb, 256, 0, stream>>>(deg, bpre, offs, cur, invd, N, E);
    fill_kernel<<<dim3((E + 255) / 256, npass), 256, 0, stream>>>(src, dst, cur, eidx, E);
    prep_wt<<<(128 * 256 + 255) / 256, 256, 0, stream>>>(W1l, W1r, WTh1, WTl1, 128);
    prep_wt<<<(128 * 256 + 255) / 256, 256, 0, stream>>>(W2l, W2r, WTh2, WTl2, 128);
    prep_wt<<<(64 * 256 + 255) / 256, 256, 0, stream>>>(W3l, W3r, WTh3, WTl3, 64);
    f2bf_kernel<<<(N * FEAT / 4 + 255) / 256, 256, 0, stream>>>(x, hbf, N * FEAT / 4);

    // layer 1: gather(xbf) -> A ; h1 = dense(A, x) -> A (fp32) + hbf (bf16)
    gather_bf_kernel<<<gblocks, 256, 0, stream>>>(hbf, offs, eidx, invd, bufA, N);
    dense_mfma<128, true, false><<<dblocks, 256, 0, stream>>>(bufA, x, WTh1, WTl1, b1, bufA, hbf, N);

    // layer 2: gather(h1bf) -> B ; h2 = dense(B, h1) -> B (fp32) + hbf (bf16)
    gather_bf_kernel<<<gblocks, 256, 0, stream>>>(hbf, offs, eidx, invd, bufB, N);
    dense_mfma<128, true, false><<<dblocks, 256, 0, stream>>>(bufB, bufA, WTh2, WTl2, b2, bufB, hbf, N);

    // layer 3: gather(h2bf) -> A ; out = log_softmax(elu(dense(A, h2))) -> d_out (fused)
    gather_bf_kernel<<<gblocks, 256, 0, stream>>>(hbf, offs, eidx, invd, bufA, N);
    dense_mfma<64, false, true><<<dblocks, 256, 0, stream>>>(bufA, bufB, WTh3, WTl3, b3, outp, nullptr, N);
}